// Round 6
// baseline (509.418 us; speedup 1.0000x reference)
//
#include <hip/hip_runtime.h>
#include <stdint.h>

#define BATCH   16384
#define INDIM   1024
#define OUTDIM  256

// concatenated-K layout (pads = 0):
//  cA4@0 len70(->72) | cD4@72 len70(->144) | cD3@144 len134(->280) | cD2@280 len128 | cD1@408 len64 (->480)
constexpr int KP = 480;

typedef __attribute__((ext_vector_type(8))) short short8;
typedef __attribute__((ext_vector_type(4))) float f32x4;

// db4 dec filters, correlation form (verified vs jax ref R1-R5)
__device__ __constant__ float LORc[8] = { 0.2303778133088965f,   0.7148465705529157f,
                                          0.6308807679298589f,  -0.027983769416859854f,
                                         -0.18703481171909309f,  0.030841381835560764f,
                                          0.0328830116668852f,  -0.010597401785069032f };
__device__ __constant__ float HIRc[8] = {-0.010597401785069032f, -0.0328830116668852f,
                                          0.030841381835560764f,  0.18703481171909309f,
                                         -0.027983769416859854f, -0.6308807679298589f,
                                          0.7148465705529157f,   -0.2303778133088965f };

__device__ __forceinline__ float symx(const float* __restrict__ in, int N, int t) {
    if (t < 0)  t = -1 - t;
    if (t >= N) t = 2 * N - 1 - t;
    return in[t];
}

__device__ __forceinline__ void dwt_level(const float* __restrict__ in, int N, int M,
                                          float* __restrict__ outA,
                                          float* __restrict__ outD, int nD, int lane) {
    for (int i = lane; i < M; i += 64) {
        const int base = 2 * i - 6;
        float a = 0.f, d = 0.f;
        if (base >= 0 && base + 7 < N) {
            #pragma unroll
            for (int k = 0; k < 8; ++k) {
                const float v = in[base + k];
                a = fmaf(v, LORc[k], a);
                d = fmaf(v, HIRc[k], d);
            }
        } else {
            #pragma unroll
            for (int k = 0; k < 8; ++k) {
                const float v = symx(in, N, base + k);
                a = fmaf(v, LORc[k], a);
                d = fmaf(v, HIRc[k], d);
            }
        }
        outA[i] = a;
        if (i < nD) outD[i] = d;
    }
}

__device__ __forceinline__ ushort f2bf_rne(float f) {
    union { float f; uint32_t u; } v; v.f = f;
    uint32_t r = v.u + 0x7fffu + ((v.u >> 16) & 1u);
    return (ushort)(r >> 16);
}
__device__ __forceinline__ float bf2f(ushort h) {
    union { uint32_t u; float f; } v; v.u = ((uint32_t)h) << 16;
    return v.f;
}

// cheap split: hi = TRUNCATED bf16 (free), lo = RNE(a - hi). Same math as R5.
__device__ __forceinline__ void splitc(float a0, float a1, uint32_t& hw, uint32_t& lw) {
    const uint32_t u0 = __float_as_uint(a0), u1 = __float_as_uint(a1);
    hw = (u0 >> 16) | (u1 & 0xffff0000u);
    const float l0 = a0 - __uint_as_float(u0 & 0xffff0000u);
    const float l1 = a1 - __uint_as_float(u1 & 0xffff0000u);
    const uint32_t v0 = __float_as_uint(l0), v1 = __float_as_uint(l1);
    const uint32_t s0 = v0 + 0x7fffu + ((v0 >> 16) & 1u);
    const uint32_t s1 = v1 + 0x7fffu + ((v1 >> 16) & 1u);
    lw = (s0 >> 16) | (s1 & 0xffff0000u);
}

// ---- prep1: blocks 0..255 -> identity DWT rows (Wc); blocks 256..375 -> pack Bp
extern "C" __global__ __launch_bounds__(256)
void prep1(const float* __restrict__ b0, const float* __restrict__ b1,
           const float* __restrict__ b2, const float* __restrict__ b3,
           const float* __restrict__ b4,
           float* __restrict__ Wc, float* __restrict__ Bp)
{
    __shared__ float buf[4][1544];
    const int tid = threadIdx.x;
    if (blockIdx.x < 256) {
        const int wid  = tid >> 6;
        const int lane = tid & 63;
        const int row  = blockIdx.x * 4 + wid;     // identity index 0..1023
        float* bufA = buf[wid];
        float* bufB = bufA + 1024;
        float* crow = Wc + (size_t)row * KP;
        for (int j = lane; j < 1024; j += 64) bufA[j] = (j == row) ? 1.f : 0.f;
        __syncthreads();
        dwt_level(bufA, 1024, 515, bufB, crow + 408, 64, lane);
        __syncthreads();
        dwt_level(bufB, 515, 261, bufA, crow + 280, 128, lane);
        __syncthreads();
        dwt_level(bufA, 261, 134, bufB, crow + 144, 134, lane);
        __syncthreads();
        dwt_level(bufB, 134, 70, crow, crow + 72, 70, lane);
        if (lane < 14) {
            const int padidx[14] = {70,71,142,143,278,279,472,473,474,475,476,477,478,479};
            crow[padidx[lane]] = 0.f;
        }
    } else {
        const int k  = (blockIdx.x - 256) * 4 + (tid >> 6);   // 0..479
        const int n0 = (tid & 63) * 4;
        float4 v = float4{0.f, 0.f, 0.f, 0.f};
        if      (k < 70)              v = *(const float4*)(b0 + (size_t)k * OUTDIM + n0);
        else if (k >= 72  && k < 142) v = *(const float4*)(b1 + (size_t)(k - 72)  * OUTDIM + n0);
        else if (k >= 144 && k < 278) v = *(const float4*)(b2 + (size_t)(k - 144) * OUTDIM + n0);
        else if (k >= 280 && k < 408) v = *(const float4*)(b3 + (size_t)(k - 280) * OUTDIM + n0);
        else if (k >= 408 && k < 472) v = *(const float4*)(b4 + (size_t)(k - 408) * OUTDIM + n0);
        *(float4*)(Bp + (size_t)k * OUTDIM + n0) = v;
    }
}

// ---- prep2 (parallel rewrite): W = Wc @ Bp, fused split+fragment-pack ------
// Bpk layout (ushort): [chunk 32][nf 16][h 2][lane 64][j 8]
//   W-row m = chunk*32 + (lane>>4)*8 + j,  n = nf*16 + (lane&15)
// grid (32 chunks, 4 n-quarters), 256 thr. Block computes W rows c*32..+31,
// cols nq*64..+63. Wc tile transposed into LDS so per-k reads are 2x b128
// broadcasts; Bp loads are independent (unrolled, pipelined).
extern "C" __global__ __launch_bounds__(256)
void prep2(const float* __restrict__ Wc, const float* __restrict__ Bp,
           ushort* __restrict__ Bpk)
{
    __shared__ float wcT[KP][32];              // 60 KB, k-major
    const int tid = threadIdx.x;
    const int c   = blockIdx.x;                // chunk 0..31
    const int nq  = blockIdx.y;                // 0..3
    const int n   = nq * 64 + (tid & 63);      // output col
    const int ms  = tid >> 6;                  // m-octet 0..3 (= kg in pack)

    // stage transpose: 8 threads per m-row
    {
        const int mm = tid >> 3, t8 = tid & 7;
        const float* src = Wc + (size_t)(c * 32 + mm) * KP;
        for (int k = t8 * 4; k < KP; k += 32) {
            const float4 v = *(const float4*)(src + k);
            wcT[k + 0][mm] = v.x; wcT[k + 1][mm] = v.y;
            wcT[k + 2][mm] = v.z; wcT[k + 3][mm] = v.w;
        }
    }
    __syncthreads();

    float acc[8] = {0,0,0,0,0,0,0,0};
    #pragma unroll 4
    for (int k = 0; k < KP; ++k) {
        const float bpv = Bp[(size_t)k * OUTDIM + n];
        const float4 w0 = *(const float4*)&wcT[k][ms * 8];
        const float4 w1 = *(const float4*)&wcT[k][ms * 8 + 4];
        acc[0] = fmaf(w0.x, bpv, acc[0]); acc[1] = fmaf(w0.y, bpv, acc[1]);
        acc[2] = fmaf(w0.z, bpv, acc[2]); acc[3] = fmaf(w0.w, bpv, acc[3]);
        acc[4] = fmaf(w1.x, bpv, acc[4]); acc[5] = fmaf(w1.y, bpv, acc[5]);
        acc[6] = fmaf(w1.z, bpv, acc[6]); acc[7] = fmaf(w1.w, bpv, acc[7]);
    }

    // split + fragment-pack: j = 0..7, kg = ms, lane = ms*16 + (n&15)
    ushort h[8], l[8];
    #pragma unroll
    for (int j = 0; j < 8; ++j) {
        h[j] = f2bf_rne(acc[j]);
        l[j] = f2bf_rne(acc[j] - bf2f(h[j]));
    }
    const int nf   = n >> 4;
    const int lane = ms * 16 + (n & 15);
    const size_t base = (size_t)c * 16384 + (size_t)(nf * 2) * 512 + (size_t)lane * 8;
    uint4 hv = { (uint32_t)h[0] | ((uint32_t)h[1] << 16), (uint32_t)h[2] | ((uint32_t)h[3] << 16),
                 (uint32_t)h[4] | ((uint32_t)h[5] << 16), (uint32_t)h[6] | ((uint32_t)h[7] << 16) };
    uint4 lv = { (uint32_t)l[0] | ((uint32_t)l[1] << 16), (uint32_t)l[2] | ((uint32_t)l[3] << 16),
                 (uint32_t)l[4] | ((uint32_t)l[5] << 16), (uint32_t)l[6] | ((uint32_t)l[7] << 16) };
    *(uint4*)(Bpk + base)       = hv;
    *(uint4*)(Bpk + base + 512) = lv;
}

// ---- main: out = x @ W, 3-term bf16-split MFMA, NO LDS, NO BARRIERS --------
// Both operand fragments are loaded per-lane directly from global:
//   A: lane reads 8 contiguous floats of one x-row (row = lane&15 within frag,
//      k-octet = lane>>4) -> split to hi/lo short8 in regs.
//   B: Bpk is pre-packed in exact fragment order -> uint4 load IS the frag.
// Block = 256 thr = 4 waves stacked in M (tile 128 x 64). Grid (128,4) = 512
// blocks -> 2 blocks/CU. Register double-buffer, depth 1.
extern "C" __global__ __launch_bounds__(256)
void wkan_direct(const float* __restrict__ x, const ushort* __restrict__ Bpk,
                 float* __restrict__ out)
{
    const int tid  = threadIdx.x;
    const int lane = tid & 63;
    const int w    = tid >> 6;                 // wave 0..3
    const int row0 = blockIdx.x * 128 + w * 32;
    const int nf0  = blockIdx.y * 4;           // cols nf0*16 .. +63

    const int r15 = lane & 15;
    const int kg  = lane >> 4;

    const float*  a0 = x + (size_t)(row0 + r15) * INDIM + kg * 8;        // m=0
    const float*  a1 = a0 + (size_t)16 * INDIM;                          // m=1
    const ushort* bp = Bpk + (size_t)nf0 * 1024 + (size_t)lane * 8;

    f32x4 acc[2][4];
    #pragma unroll
    for (int m = 0; m < 2; ++m)
        #pragma unroll
        for (int f = 0; f < 4; ++f) acc[m][f] = f32x4{0.f, 0.f, 0.f, 0.f};

    float4 ar[2][2][2];   // [buf][m][half]
    uint4  br[2][4][2];   // [buf][f][h]  -- raw frag = MFMA operand

    // prologue: chunk 0 -> buf 0
    #pragma unroll
    for (int f = 0; f < 4; ++f) {
        br[0][f][0] = *(const uint4*)(bp + f * 1024);
        br[0][f][1] = *(const uint4*)(bp + f * 1024 + 512);
    }
    ar[0][0][0] = *(const float4*)(a0);
    ar[0][0][1] = *(const float4*)(a0 + 4);
    ar[0][1][0] = *(const float4*)(a1);
    ar[0][1][1] = *(const float4*)(a1 + 4);

    #pragma unroll 2
    for (int c = 0; c < 32; ++c) {
        const int p = c & 1, q = p ^ 1;

        if (c < 31) {   // issue next chunk's loads (fly under this chunk's MFMA)
            const ushort* bn = bp + (size_t)(c + 1) * 16384;
            #pragma unroll
            for (int f = 0; f < 4; ++f) {
                br[q][f][0] = *(const uint4*)(bn + f * 1024);
                br[q][f][1] = *(const uint4*)(bn + f * 1024 + 512);
            }
            const float* an0 = a0 + (size_t)(c + 1) * 32;
            const float* an1 = a1 + (size_t)(c + 1) * 32;
            ar[q][0][0] = *(const float4*)(an0);
            ar[q][0][1] = *(const float4*)(an0 + 4);
            ar[q][1][0] = *(const float4*)(an1);
            ar[q][1][1] = *(const float4*)(an1 + 4);
        }

        // split A(c) to hi/lo fragments
        short8 afr[2][2];
        #pragma unroll
        for (int m = 0; m < 2; ++m) {
            union { uint32_t u[4]; short8 s; } uh, ul;
            splitc(ar[p][m][0].x, ar[p][m][0].y, uh.u[0], ul.u[0]);
            splitc(ar[p][m][0].z, ar[p][m][0].w, uh.u[1], ul.u[1]);
            splitc(ar[p][m][1].x, ar[p][m][1].y, uh.u[2], ul.u[2]);
            splitc(ar[p][m][1].z, ar[p][m][1].w, uh.u[3], ul.u[3]);
            afr[m][0] = uh.s;
            afr[m][1] = ul.s;
        }

        #pragma unroll
        for (int m = 0; m < 2; ++m)
            #pragma unroll
            for (int f = 0; f < 4; ++f) {
                union { uint4 u; short8 s; } b0c, b1c;
                b0c.u = br[p][f][0];
                b1c.u = br[p][f][1];
                acc[m][f] = __builtin_amdgcn_mfma_f32_16x16x32_bf16(afr[m][0], b0c.s, acc[m][f], 0, 0, 0);
                acc[m][f] = __builtin_amdgcn_mfma_f32_16x16x32_bf16(afr[m][0], b1c.s, acc[m][f], 0, 0, 0);
                acc[m][f] = __builtin_amdgcn_mfma_f32_16x16x32_bf16(afr[m][1], b0c.s, acc[m][f], 0, 0, 0);
            }
    }

    // C write: D[col = lane&15, row = (lane>>4)*4 + r]  (verified R3-R5)
    #pragma unroll
    for (int m = 0; m < 2; ++m)
        #pragma unroll
        for (int f = 0; f < 4; ++f) {
            const int col  = nf0 * 16 + f * 16 + r15;
            const int rowb = row0 + m * 16 + kg * 4;
            #pragma unroll
            for (int r = 0; r < 4; ++r)
                out[(size_t)(rowb + r) * OUTDIM + col] = acc[m][f][r];
        }
}

// ================= fallback: R1 fused kernel (if ws too small) ===============
constexpr int F_ROWS = 32;
constexpr int F_KP   = 472;

__device__ __forceinline__ void dwt_level_f(const float* __restrict__ in, int N, int M,
                                            float* __restrict__ outA,
                                            float* __restrict__ outD, int nD, int ht) {
    for (int i = ht; i < M; i += 128) {
        const int base = 2 * i - 6;
        float a = 0.f, d = 0.f;
        #pragma unroll
        for (int k = 0; k < 8; ++k) {
            const float v = symx(in, N, base + k);
            a = fmaf(v, LORc[k], a);
            d = fmaf(v, HIRc[k], d);
        }
        outA[i] = a;
        if (i < nD) outD[i] = d;
    }
}

extern "C" __global__ __launch_bounds__(256, 2)
void wkan_fused(const float* __restrict__ x,
                const float* __restrict__ b0, const float* __restrict__ b1,
                const float* __restrict__ b2, const float* __restrict__ b3,
                const float* __restrict__ b4,
                float* __restrict__ out)
{
    extern __shared__ float smem[];
    float* coef = smem;
    float* wbuf = smem + F_ROWS * F_KP;

    const int tid  = threadIdx.x;
    const int row0 = blockIdx.x * F_ROWS;

    for (int i = tid; i < F_ROWS * F_KP / 4; i += 256)
        ((float4*)coef)[i] = float4{0.f, 0.f, 0.f, 0.f};
    __syncthreads();

    const int slot = tid >> 7;
    const int ht   = tid & 127;
    float* bufA = wbuf + slot * 1544;
    float* bufB = bufA + 1024;

    for (int it = 0; it < F_ROWS / 2; ++it) {
        const int r = it * 2 + slot;
        float* crow = coef + r * F_KP;
        const float* xrow = x + (size_t)(row0 + r) * INDIM;
        ((float4*)bufA)[ht]       = ((const float4*)xrow)[ht];
        ((float4*)bufA)[ht + 128] = ((const float4*)xrow)[ht + 128];
        __syncthreads();
        dwt_level_f(bufA, 1024, 515, bufB, crow + 408, 64, ht);
        __syncthreads();
        dwt_level_f(bufB, 515, 261, bufA, crow + 280, 128, ht);
        __syncthreads();
        dwt_level_f(bufA, 261, 134, bufB, crow + 144, 134, ht);
        __syncthreads();
        dwt_level_f(bufB, 134, 70, crow, crow + 72, 70, ht);
        __syncthreads();
    }

    const int rg = tid >> 5;
    const int cg = tid & 31;
    float acc[4][8];
    #pragma unroll
    for (int r = 0; r < 4; ++r)
        #pragma unroll
        for (int c = 0; c < 8; ++c) acc[r][c] = 0.f;

    const float* Bs[5]  = { b0, b1, b2, b3, b4 };
    const int    off[5] = { 0, 72, 144, 280, 408 };
    const int    l4[5]  = { 72, 72, 136, 128, 64 };

    for (int s = 0; s < 5; ++s) {
        const float* __restrict__ B = Bs[s];
        const int o = off[s], L = l4[s];
        for (int k = 0; k < L; k += 4) {
            float4 bb[4][2];
            #pragma unroll
            for (int kk = 0; kk < 4; ++kk) {
                const float* bpp = B + (size_t)(k + kk) * OUTDIM + cg * 8;
                bb[kk][0] = *(const float4*)(bpp);
                bb[kk][1] = *(const float4*)(bpp + 4);
            }
            #pragma unroll
            for (int rr = 0; rr < 4; ++rr) {
                const float4 c4 = *(const float4*)(coef + (rg * 4 + rr) * F_KP + o + k);
                const float cv[4] = { c4.x, c4.y, c4.z, c4.w };
                #pragma unroll
                for (int kk = 0; kk < 4; ++kk) {
                    acc[rr][0] = fmaf(cv[kk], bb[kk][0].x, acc[rr][0]);
                    acc[rr][1] = fmaf(cv[kk], bb[kk][0].y, acc[rr][1]);
                    acc[rr][2] = fmaf(cv[kk], bb[kk][0].z, acc[rr][2]);
                    acc[rr][3] = fmaf(cv[kk], bb[kk][0].w, acc[rr][3]);
                    acc[rr][4] = fmaf(cv[kk], bb[kk][1].x, acc[rr][4]);
                    acc[rr][5] = fmaf(cv[kk], bb[kk][1].y, acc[rr][5]);
                    acc[rr][6] = fmaf(cv[kk], bb[kk][1].z, acc[rr][6]);
                    acc[rr][7] = fmaf(cv[kk], bb[kk][1].w, acc[rr][7]);
                }
            }
        }
    }

    #pragma unroll
    for (int rr = 0; rr < 4; ++rr) {
        float* op = out + (size_t)(row0 + rg * 4 + rr) * OUTDIM + cg * 8;
        *(float4*)(op)     = float4{ acc[rr][0], acc[rr][1], acc[rr][2], acc[rr][3] };
        *(float4*)(op + 4) = float4{ acc[rr][4], acc[rr][5], acc[rr][6], acc[rr][7] };
    }
}

// =============================================================================
extern "C" void kernel_launch(void* const* d_in, const int* in_sizes, int n_in,
                              void* d_out, int out_size, void* d_ws, size_t ws_size,
                              hipStream_t stream) {
    const float* x  = (const float*)d_in[0];
    const float* b0 = (const float*)d_in[1];
    const float* b1 = (const float*)d_in[2];
    const float* b2 = (const float*)d_in[3];
    const float* b3 = (const float*)d_in[4];
    const float* b4 = (const float*)d_in[5];
    float* out = (float*)d_out;

    const size_t nWc  = (size_t)1024 * KP;            // fp32
    const size_t nBp  = (size_t)KP * OUTDIM;          // fp32
    const size_t nBpk = (size_t)1024 * OUTDIM * 2;    // ushort (hi+lo)
    const size_t need = (nWc + nBp) * 4 + nBpk * 2;   // ~3.5 MB

    if (ws_size >= need) {
        float*  Wc  = (float*)d_ws;
        float*  Bp  = Wc + nWc;
        ushort* Bpk = (ushort*)(Bp + nBp);

        hipLaunchKernelGGL(prep1, dim3(376), dim3(256), 0, stream,
                           b0, b1, b2, b3, b4, Wc, Bp);
        hipLaunchKernelGGL(prep2, dim3(32, 4), dim3(256), 0, stream, Wc, Bp, Bpk);
        hipLaunchKernelGGL(wkan_direct, dim3(BATCH / 128, 4), dim3(256), 0, stream,
                           x, Bpk, out);
    } else {
        const size_t shmem = (size_t)(F_ROWS * F_KP + 2 * 1544) * sizeof(float);
        hipLaunchKernelGGL(wkan_fused, dim3(BATCH / F_ROWS), dim3(256), shmem, stream,
                           x, b0, b1, b2, b3, b4, out);
    }
}